// Round 9
// baseline (350.782 us; speedup 1.0000x reference)
//
#include <hip/hip_runtime.h>
#include <math.h>

#define B_ 4
#define S_ 2048
#define E_ 1024
#define H_ 16
#define D_ 64
#define MRD 32

typedef __bf16 bf16x8 __attribute__((ext_vector_type(8)));
typedef float f32x4 __attribute__((ext_vector_type(4)));
typedef float f32x16 __attribute__((ext_vector_type(16)));
typedef unsigned short us8 __attribute__((ext_vector_type(8)));
typedef unsigned short us4 __attribute__((ext_vector_type(4)));

union frag_cvt { us8 u; bf16x8 b; };
union h_cvt { __bf16 h; unsigned short u; };

__device__ __forceinline__ unsigned short bhi(float x) {
    h_cvt c; c.h = (__bf16)x; return c.u;
}
__device__ __forceinline__ float bf16_f(unsigned short h) {
    union { unsigned int u; float f; } c;
    c.u = ((unsigned int)h) << 16;
    return c.f;
}

__device__ __forceinline__ void async_copy16(const void* g, void* l) {
    __builtin_amdgcn_global_load_lds(
        (const __attribute__((address_space(1))) void*)g,
        (__attribute__((address_space(3))) void*)l,
        16, 0, 0);
}

__device__ __forceinline__ f32x16 mf32(const frag_cvt& a, const frag_cvt& b, f32x16 c) {
    return __builtin_amdgcn_mfma_f32_32x32x16_bf16(a.b, b.b, c, 0, 0, 0);
}

#define QSCL 0.18033688f    // 0.125 * log2(e) — folded into Qb at projection
#define L2E  1.44269504f

// ---------------------------------------------------------------------------
// Convert pass (ROUND-0): fp32 -> bf16, GROUP-SWIZZLED for gemm_qkv5 staging.
// ---------------------------------------------------------------------------
__global__ __launch_bounds__(128) void cvt_bf16(
    const float* __restrict__ in, unsigned short* __restrict__ out, int K)
{
    const int r  = blockIdx.x;
    const int k8 = threadIdx.x * 8;
    if (k8 >= K) return;
    const float* p = in + (size_t)r * K + k8;
    float4 a = *(const float4*)p;
    float4 b = *(const float4*)(p + 4);
    float xs[8] = {a.x, a.y, a.z, a.w, b.x, b.y, b.z, b.w};
    us8 hu;
#pragma unroll
    for (int j = 0; j < 8; ++j) hu[j] = bhi(xs[j]);
    const int pos = (k8 & ~31) + ((((k8 >> 3) & 3) ^ (r & 3)) * 8);
    *(us8*)&out[(size_t)r * K + pos] = hu;
}

// ---------------------------------------------------------------------------
// Split pass (ROUND-0): fp32 -> {hi|lo} bf16, group-swizzled (out_w only).
// ---------------------------------------------------------------------------
__global__ __launch_bounds__(128) void split_hilo(
    const float* __restrict__ in, unsigned short* __restrict__ out, int K)
{
    const int r  = blockIdx.x;
    const int k8 = threadIdx.x * 8;
    if (k8 >= K) return;
    const float* p = in + (size_t)r * K + k8;
    float4 a = *(const float4*)p;
    float4 b = *(const float4*)(p + 4);
    float xs[8] = {a.x, a.y, a.z, a.w, b.x, b.y, b.z, b.w};
    us8 hu, lu;
#pragma unroll
    for (int j = 0; j < 8; ++j) {
        unsigned short hb = bhi(xs[j]);
        hu[j] = hb;
        lu[j] = bhi(xs[j] - bf16_f(hb));
    }
    const int pos = (k8 & ~31) + ((((k8 >> 3) & 3) ^ (r & 3)) * 8);
    *(us8*)&out[(size_t)r * 2 * K + pos]     = hu;
    *(us8*)&out[(size_t)r * 2 * K + K + pos] = lu;
}

// ---------------------------------------------------------------------------
// QKV GEMM (ROUND-0 body + T1 XCD swizzle: each XCD owns an m-stripe so
// A-panels stay L2-resident; bijective since nwg=1536 % 8 == 0).
// ---------------------------------------------------------------------------
__global__ __launch_bounds__(256, 2) void gemm_qkv5(
    const unsigned short* __restrict__ Ab, const unsigned short* __restrict__ Bb,
    const float* __restrict__ bias, unsigned short* __restrict__ Qb,
    unsigned short* __restrict__ K2, unsigned short* __restrict__ Vt2,
    int M, int N, int K)
{
    __shared__ unsigned short At[128 * 32];
    __shared__ unsigned short Bt[128 * 32];

    const int t    = threadIdx.x;
    const int w    = t >> 6;
    const int lane = t & 63;
    const int ln   = lane & 15;
    const int quad = lane >> 4;
    const int wm   = w >> 1;
    const int wn   = w & 1;

    // XCD-aware block swizzle (T1): XCD i%8 -> contiguous m-stripe
    const int nbx = gridDim.x, nby = gridDim.y;
    int lin = blockIdx.x + blockIdx.y * nbx;
    const int per = (nbx * nby) >> 3;
    lin = (lin & 7) * per + (lin >> 3);
    const int m0 = (lin / nby) * 128;
    const int n0 = (lin % nby) * 128;

    const int srow = w * 16 + (lane >> 2);
    const int scol = (lane & 3) * 8;
    const unsigned short* Abase = Ab + (size_t)(m0 + srow) * K + scol;
    const unsigned short* Bbase = Bb + (size_t)(n0 + srow) * K + scol;
    const int wlds = (w * 16) * 32;
    const int fro  = (quad ^ (ln & 3)) * 8;

    f32x4 acc[4][4];
#pragma unroll
    for (int i = 0; i < 4; ++i)
#pragma unroll
        for (int j = 0; j < 4; ++j)
            acc[i][j] = (f32x4){0.f, 0.f, 0.f, 0.f};

    for (int kk = 0; kk < K; kk += 32) {
        __syncthreads();
#pragma unroll
        for (int c = 0; c < 2; ++c) {
            const size_t ro = (size_t)(c * 64) * K;
            const int lo = c * 64 * 32 + wlds;
            async_copy16(Abase + ro + kk, &At[lo]);
            async_copy16(Bbase + ro + kk, &Bt[lo]);
        }
        __syncthreads();

        frag_cvt ah[4], bh[4];
#pragma unroll
        for (int i = 0; i < 4; ++i) {
            ah[i].u = *(const us8*)&At[(wm * 64 + i * 16 + ln) * 32 + fro];
            bh[i].u = *(const us8*)&Bt[(wn * 64 + i * 16 + ln) * 32 + fro];
        }
#pragma unroll
        for (int i = 0; i < 4; ++i)
#pragma unroll
            for (int j = 0; j < 4; ++j)
                acc[i][j] = __builtin_amdgcn_mfma_f32_16x16x32_bf16(
                    ah[i].b, bh[j].b, acc[i][j], 0, 0, 0);
    }

    if (n0 < E_) {
#pragma unroll
        for (int j = 0; j < 4; ++j) {
            const int col = n0 + wn * 64 + j * 16 + ln;
            const float bv = bias[col];
            const int h = (col & (E_ - 1)) >> 6, d = col & 63;
#pragma unroll
            for (int i = 0; i < 4; ++i) {
#pragma unroll
                for (int r = 0; r < 4; ++r) {
                    const int row = m0 + wm * 64 + i * 16 + quad * 4 + r;
                    const int b = row >> 11, s = row & (S_ - 1);
                    Qb[((size_t)(b * 16 + h) * S_ + s) * 64 + d] =
                        bhi((acc[i][j][r] + bv) * QSCL);
                }
            }
        }
    } else if (n0 < 2 * E_) {
#pragma unroll
        for (int j = 0; j < 4; ++j) {
            const int col = n0 + wn * 64 + j * 16 + ln;
            const float bv = bias[col];
            const int h = (col & (E_ - 1)) >> 6, d = col & 63;
#pragma unroll
            for (int i = 0; i < 4; ++i) {
#pragma unroll
                for (int r = 0; r < 4; ++r) {
                    const int row = m0 + wm * 64 + i * 16 + quad * 4 + r;
                    const int b = row >> 11, s = row & (S_ - 1);
                    K2[((size_t)(b * 16 + h) * S_ + s) * 64 +
                       (((d >> 3) ^ (s & 7)) * 8) + (d & 7)] =
                        bhi(acc[i][j][r] + bv);
                }
            }
        }
    } else {
#pragma unroll
        for (int j = 0; j < 4; ++j) {
            const int col = n0 + wn * 64 + j * 16 + ln;
            const float bv = bias[col];
            const int h = (col & (E_ - 1)) >> 6, d = col & 63;
#pragma unroll
            for (int i = 0; i < 4; ++i) {
                const int row0 = m0 + wm * 64 + i * 16 + quad * 4;
                const int b = row0 >> 11, s0 = row0 & (S_ - 1);
                const int tile = s0 >> 6;
                const int g = (s0 >> 3) & 7;
                us4 o;
#pragma unroll
                for (int r = 0; r < 4; ++r) o[r] = bhi(acc[i][j][r] + bv);
                *(us4*)&Vt2[(size_t)(b * 16 + h) * S_ * 64 + tile * 4096 +
                            d * 64 + ((g ^ (d & 7)) * 8) + (quad & 1) * 4] = o;
            }
        }
    }
}

// ---------------------------------------------------------------------------
// Flash attention v7: identical per-wave data-path to the twice-verified
// v6.3 (builtin permlane, MFMA row-sum, __syncthreads boundary, NO asm).
// Structural changes only:
//   - QBLK 256, 8 waves/block: K/V staged once per 2x q-work; barriers and
//     stage-issue per q halved; 2 blocks/CU x 8 waves = ~50% occupancy.
//   - per-wave inband test (qw0): exactly 2 in-band tiles per wave.
//   - stage split: waves 0-3 stage K (2 segments each), waves 4-7 stage V.
// ---------------------------------------------------------------------------
__global__ __launch_bounds__(512, 4) void attn_mfma7(
    const unsigned short* __restrict__ Qb, const unsigned short* __restrict__ K2,
    const unsigned short* __restrict__ Vt2, const float* __restrict__ rel_bias,
    unsigned short* __restrict__ ctx2)
{
    __shared__ unsigned short Kt[2][4096];   // 2 x 8 KB  (64 keys x 64 d)
    __shared__ unsigned short Vt[2][4096];   // 2 x 8 KB  (V^T: 64 d x 64 keys)
    __shared__ float bias_s[65];

    const int t    = threadIdx.x;
    const int w    = t >> 6;                 // 0..7
    const int lane = t & 63;
    const int l31  = lane & 31;
    const int h    = lane >> 5;
    const int swzk = lane & 7;               // (row&7) for this lane's rows

    const int bh  = blockIdx.x;
    const int b   = bh >> 4;
    const int hh  = bh & 15;
    const int q0  = blockIdx.y * 256;
    const int qw0 = q0 + w * 32;             // this wave's 32 q-rows

    if (t < 65) {
        float s = 0.f;
#pragma unroll
        for (int j = 0; j < 16; ++j) s += rel_bias[t * 16 + j];
        bias_s[t] = s * (L2E / 16.f);
    }

    // Q as B-frag: col q = l31 (rows qw0+l31), k = h*8+e per 16-d chunk.
    frag_cvt qf[4];
    {
        const unsigned short* qp =
            Qb + ((size_t)bh * S_ + qw0 + l31) * 64 + h * 8;
#pragma unroll
        for (int ks = 0; ks < 4; ++ks) qf[ks].u = *(const us8*)(qp + ks * 16);
    }

    frag_cvt ones;
#pragma unroll
    for (int j = 0; j < 8; ++j) ones.u[j] = 0x3F80;

    f32x16 Z;
#pragma unroll
    for (int i = 0; i < 16; ++i) Z[i] = 0.f;
    f32x16 O0 = Z, O1 = Z, lacc = Z;

    const unsigned short* Kg = K2  + (size_t)bh * S_ * 64;
    const unsigned short* Vg = Vt2 + (size_t)bh * S_ * 64;

    // ---- prologue: stage tile 0 (waves 0-3: K, waves 4-7: V) --------------
    {
        const int seg = (w & 3) * 1024;
        if (w < 4) {
            async_copy16(Kg + seg + lane * 8,       &Kt[0][seg]);
            async_copy16(Kg + seg + 512 + lane * 8, &Kt[0][seg + 512]);
        } else {
            async_copy16(Vg + seg + lane * 8,       &Vt[0][seg]);
            async_copy16(Vg + seg + 512 + lane * 8, &Vt[0][seg + 512]);
        }
    }
    __syncthreads();

    for (int kt0 = 0; kt0 < 32; ++kt0) {
        const int cur = kt0 & 1;
        const int k0  = kt0 * 64;

        // issue next-tile stage early (T14): hides under this tile's compute
        if (kt0 + 1 < 32) {
            const unsigned short* kg = Kg + (size_t)(k0 + 64) * 64;
            const unsigned short* vg = Vg + (size_t)(k0 + 64) * 64;
            const int seg = (w & 3) * 1024;
            if (w < 4) {
                async_copy16(kg + seg + lane * 8,       &Kt[cur ^ 1][seg]);
                async_copy16(kg + seg + 512 + lane * 8, &Kt[cur ^ 1][seg + 512]);
            } else {
                async_copy16(vg + seg + lane * 8,       &Vt[cur ^ 1][seg]);
                async_copy16(vg + seg + 512 + lane * 8, &Vt[cur ^ 1][seg + 512]);
            }
        }

        // ---- QK^T swapped: sa = K-tile-half · Q^T -------------------------
        f32x16 sa0 = Z, sa1 = Z;
#pragma unroll
        for (int ks = 0; ks < 4; ++ks) {
            frag_cvt kh0, kh1;
            const int go = ((ks * 2 + h) ^ swzk) * 8;   // d-granule position
            kh0.u = *(const us8*)&Kt[cur][l31 * 64 + go];
            kh1.u = *(const us8*)&Kt[cur][(32 + l31) * 64 + go];
            sa0 = mf32(kh0, qf[ks], sa0);
            sa1 = mf32(kh1, qf[ks], sa1);
        }

        // ---- softmax in registers (per-wave inband; no asm) ---------------
        // out-of-band proof: k0 < qw0-95 -> all rel >= 33 (clamp +MRD);
        //                    k0 > qw0+63 -> all rel <= -33 (clamp -MRD).
        const bool inband = (k0 >= qw0 - 95) && (k0 <= qw0 + 63);
        float cb = 0.f;
        if (!inband) cb = bias_s[(k0 < qw0) ? 64 : 0];
        const int q = qw0 + l31;

        unsigned int Wd[2][4][2];
#pragma unroll
        for (int kt = 0; kt < 2; ++kt) {
#pragma unroll
            for (int B2 = 0; B2 < 4; ++B2) {
#pragma unroll
                for (int p = 0; p < 2; ++p) {
                    unsigned int word = 0;
#pragma unroll
                    for (int rp = 0; rp < 2; ++rp) {
                        const int reg = B2 * 4 + p * 2 + rp;
                        const float sv = (kt == 0) ? sa0[reg] : sa1[reg];
                        float s2;
                        if (inband) {
                            const int key = k0 + kt * 32 + B2 * 8 + h * 4 + p * 2 + rp;
                            int rel = q - key;
                            rel = (rel < -MRD) ? -MRD : (rel > MRD ? MRD : rel);
                            s2 = sv + bias_s[rel + MRD];
                        } else {
                            s2 = sv + cb;
                        }
                        const float e = __builtin_amdgcn_exp2f(s2);
                        word |= ((unsigned int)bhi(e)) << (16 * rp);
                    }
                    Wd[kt][B2][p] = word;
                }
            }
        }

        // ---- PV + row-sum: A-frag via builtin permlane32_swap -------------
#pragma unroll
        for (int m = 0; m < 4; ++m) {
            const int kt  = m >> 1;
            const int sel = (m & 1) * 2;
            auto r0 = __builtin_amdgcn_permlane32_swap(
                Wd[kt][sel][0], Wd[kt][sel + 1][0], false, false);
            auto r1 = __builtin_amdgcn_permlane32_swap(
                Wd[kt][sel][1], Wd[kt][sel + 1][1], false, false);
            frag_cvt pa;
            union { us8 v; unsigned int d[4]; } uu;
            uu.d[0] = (unsigned int)r0[0];
            uu.d[1] = (unsigned int)r1[0];
            uu.d[2] = (unsigned int)r0[1];
            uu.d[3] = (unsigned int)r1[1];
            pa.u = uu.v;

            lacc = mf32(pa, ones, lacc);                // row-sum, matrix pipe

            const int gv = ((m * 2 + h) ^ swzk) * 8;    // key-granule position
            frag_cvt v0, v1;
            v0.u = *(const us8*)&Vt[cur][l31 * 64 + gv];
            v1.u = *(const us8*)&Vt[cur][(32 + l31) * 64 + gv];
            O0 = mf32(pa, v0, O0);
            O1 = mf32(pa, v1, O1);
        }

        // ---- boundary: full drain (vmcnt+lgkmcnt) + barrier — race-free ---
        __syncthreads();
    }

    // ---- epilogue: lacc C-layout row mapping == O's -> direct reciprocal --
    float invq[16];
#pragma unroll
    for (int reg = 0; reg < 16; ++reg)
        invq[reg] = 1.f / lacc[reg];

#pragma unroll
    for (int dblk = 0; dblk < 2; ++dblk) {
#pragma unroll
        for (int reg = 0; reg < 16; ++reg) {
            const int qrow = qw0 + (reg & 3) + 8 * (reg >> 2) + 4 * h;
            const float v = ((dblk == 0) ? O0[reg] : O1[reg]) * invq[reg];
            const unsigned short hb = bhi(v);
            const int k = hh * 64 + dblk * 32 + l31;
            // A2c group-swizzle: pos = (k&~31) + ((kg ^ (q&3))*8) + (k&7)
            const int pos = (k & ~31) + (((l31 >> 3) ^ (reg & 3)) * 8) + (k & 7);
            const size_t rb = (size_t)(b * S_ + qrow) * (2 * E_);
            ctx2[rb + pos]      = hb;
            ctx2[rb + E_ + pos] = bhi(v - bf16_f(hb));
        }
    }
}

// ---------------------------------------------------------------------------
// Output projection (ROUND-0 body + T1 XCD swizzle, nwg=512 % 8 == 0).
// ---------------------------------------------------------------------------
__global__ __launch_bounds__(256, 2) void gemm_out4(
    const unsigned short* __restrict__ A2, const unsigned short* __restrict__ B2,
    const float* __restrict__ bias, float* __restrict__ C,
    int M, int N, int K)
{
    __shared__ unsigned short Ath[128 * 32], Atl[128 * 32];
    __shared__ unsigned short Bth[128 * 32], Btl[128 * 32];

    const int t    = threadIdx.x;
    const int w    = t >> 6;
    const int lane = t & 63;
    const int ln   = lane & 15;
    const int quad = lane >> 4;
    const int wm   = w >> 1;
    const int wn   = w & 1;

    // XCD-aware block swizzle (T1)
    const int nbx = gridDim.x, nby = gridDim.y;
    int lin = blockIdx.x + blockIdx.y * nbx;
    const int per = (nbx * nby) >> 3;
    lin = (lin & 7) * per + (lin >> 3);
    const int m0 = (lin / nby) * 128;
    const int n0 = (lin % nby) * 128;

    const int K2s  = 2 * K;

    const int srow = w * 16 + (lane >> 2);
    const int scol = (lane & 3) * 8;
    const unsigned short* Abase = A2 + (size_t)(m0 + srow) * K2s + scol;
    const unsigned short* Bbase = B2 + (size_t)(n0 + srow) * K2s + scol;
    const int wlds = (w * 16) * 32;
    const int fro  = (quad ^ (ln & 3)) * 8;

    f32x4 acc[4][4];
#pragma unroll
    for (int i = 0; i < 4; ++i)
#pragma unroll
        for (int j = 0; j < 4; ++j)
            acc[i][j] = (f32x4){0.f, 0.f, 0.f, 0.f};

    for (int kk = 0; kk < K; kk += 32) {
        __syncthreads();
#pragma unroll
        for (int c = 0; c < 2; ++c) {
            const size_t ro = (size_t)(c * 64) * K2s;
            const int lo = c * 64 * 32 + wlds;
            async_copy16(Abase + ro + kk,     &Ath[lo]);
            async_copy16(Abase + ro + K + kk, &Atl[lo]);
            async_copy16(Bbase + ro + kk,     &Bth[lo]);
            async_copy16(Bbase + ro + K + kk, &Btl[lo]);
        }
        __syncthreads();

        frag_cvt ah[4], al[4], bh[4], bl[4];
#pragma unroll
        for (int i = 0; i < 4; ++i) {
            const int ar = (wm * 64 + i * 16 + ln) * 32 + fro;
            const int br = (wn * 64 + i * 16 + ln) * 32 + fro;
            ah[i].u = *(const us8*)&Ath[ar];
            al[i].u = *(const us8*)&Atl[ar];
            bh[i].u = *(const us8*)&Bth[br];
            bl[i].u = *(const us8*)&Btl[br];
        }
#pragma unroll
        for (int i = 0; i < 4; ++i)
#pragma unroll
            for (int j = 0; j < 4; ++j) {
                acc[i][j] = __builtin_amdgcn_mfma_f32_16x16x32_bf16(
                    ah[i].b, bh[j].b, acc[i][j], 0, 0, 0);
                acc[i][j] = __builtin_amdgcn_mfma_f32_16x16x32_bf16(
                    ah[i].b, bl[j].b, acc[i][j], 0, 0, 0);
                acc[i][j] = __builtin_amdgcn_mfma_f32_16x16x32_bf16(
                    al[i].b, bh[j].b, acc[i][j], 0, 0, 0);
            }
    }

#pragma unroll
    for (int j = 0; j < 4; ++j) {
        const int col = n0 + wn * 64 + j * 16 + ln;
        const float bv = bias[col];
#pragma unroll
        for (int i = 0; i < 4; ++i) {
            const int row = m0 + wm * 64 + i * 16 + quad * 4;
#pragma unroll
            for (int r = 0; r < 4; ++r)
                C[(size_t)(row + r) * N + col] = acc[i][j][r] + bv;
        }
    }
}

// ---------------------------------------------------------------------------
extern "C" void kernel_launch(void* const* d_in, const int* in_sizes, int n_in,
                              void* d_out, int out_size, void* d_ws, size_t ws_size,
                              hipStream_t stream)
{
    const float* x         = (const float*)d_in[0];
    const float* in_proj_w = (const float*)d_in[1];
    const float* in_proj_b = (const float*)d_in[2];
    const float* out_w     = (const float*)d_in[3];
    const float* out_b     = (const float*)d_in[4];
    const float* rel_bias  = (const float*)d_in[5];
    float* out = (float*)d_out;

    const int M = B_ * S_;                         // 8192
    const size_t PH = (size_t)B_ * H_ * S_ * 64;   // 8.39M ushorts

    // workspace (~112 MB) — ROUND-0 layout
    unsigned short* Qb   = (unsigned short*)d_ws;          // 16.8 MB
    unsigned short* K2   = Qb + PH;                        // 16.8 MB
    unsigned short* Vt2  = K2 + PH;                        // 16.8 MB
    unsigned short* A2c  = Vt2 + PH;                       // [M][2E] 33.6 MB
    unsigned short* Axb  = A2c + (size_t)M * 2 * E_;       // [M][E]  16.8 MB
    unsigned short* Wqkv = Axb + (size_t)M * E_;           // [3E][E]  6.3 MB
    unsigned short* W2o  = Wqkv + (size_t)3 * E_ * E_;     // [E][2E]  4.2 MB

    // 1) convert x and in_proj_w to bf16 (group-swizzled for gemm staging)
    cvt_bf16<<<M,      128, 0, stream>>>(x,         Axb,  E_);
    cvt_bf16<<<3 * E_, 128, 0, stream>>>(in_proj_w, Wqkv, E_);

    // 2) QKV projection (round-0 kernel + XCD swizzle) -> Qb / K2 / Vt2
    {
        dim3 grid(M / 128, (3 * E_) / 128);   // 64 x 24 = 1536 blocks
        gemm_qkv5<<<grid, 256, 0, stream>>>(Axb, Wqkv, in_proj_b, Qb, K2, Vt2,
                                            M, 3 * E_, E_);
    }
    // 3) attention v7 (QBLK=256, 8 waves, v6.3 data-path) -> A2c
    {
        dim3 grid(B_ * H_, S_ / 256);         // 64 x 8 = 512 blocks
        attn_mfma7<<<grid, 512, 0, stream>>>(Qb, K2, Vt2, rel_bias, A2c);
    }
    // 4) split out_w, output projection (round-0 kernel + XCD swizzle)
    split_hilo<<<E_, 128, 0, stream>>>(out_w, W2o, E_);
    {
        dim3 grid(M / 128, E_ / 128);         // 64 x 8 = 512 blocks
        gemm_out4<<<grid, 256, 0, stream>>>(A2c, W2o, out_b, out, M, E_, E_);
    }
}